// Round 5
// baseline (185.640 us; speedup 1.0000x reference)
//
#include <hip/hip_runtime.h>
#include <cmath>

#define H_ 128
#define W_ 128
#define HW_ 16384
#define C_ 64
#define N_ 8
#define BN_EPS 1e-5f

typedef __attribute__((ext_vector_type(8))) short short8;
typedef __attribute__((ext_vector_type(4))) float float4_;

__device__ inline short f2bf(float f) {
    unsigned u = __builtin_bit_cast(unsigned, f);
    u += 0x7fffu + ((u >> 16) & 1u);     // RNE
    return (short)(u >> 16);
}
__device__ inline float bf2f(short s) {
    unsigned u = ((unsigned)(unsigned short)s) << 16;
    return __builtin_bit_cast(float, u);
}

// ---- workspace layout (bytes) ----
#define OFFB_OFS   0
#define XB8_OFS    9437184
#define XR8_OFS    26214400
#define WDEFB_OFS  42991616
#define BT27_OFS   43065344
#define BT9_OFS    43102720

// ---------------- weight prep ----------------
__global__ __launch_bounds__(256) void prep_w(
    const float* __restrict__ w_off, const float* __restrict__ w_def,
    const float* __restrict__ w1, short* __restrict__ wdefB,
    short* __restrict__ bt27, short* __restrict__ bt9)
{
    int i = blockIdx.x * 256 + threadIdx.x;
    if (i < 36864) {
        int o = i / 576, r = i - o*576, t = r >> 6, c = r & 63;
        wdefB[i] = f2bf(w_def[o*576 + c*9 + t]);
    } else if (i < 36864 + 18688) {
        int j = i - 36864;
        int oc = j / 584, K = j - oc*584;
        float v = 0.f;
        if (oc < 27 && K < 576) { int t = K >> 6, c = K & 63; v = w_off[oc*576 + c*9 + t]; }
        bt27[j] = f2bf(v);
    } else if (i < 36864 + 18688 + 9344) {
        int j = i - 36864 - 18688;
        int oc = j / 584, K = j - oc*584;
        float v = 0.f;
        if (oc < 9 && K < 576) { int t = K >> 6, c = K & 63; v = w1[oc*576 + c*9 + t]; }
        bt9[j] = f2bf(v);
    }
}

// ---------------- x -> NC8HW8 bf16 ----------------
__global__ __launch_bounds__(256) void convert_x(
    const float* __restrict__ x, short8* __restrict__ xb8)
{
    int idx = blockIdx.x * 256 + threadIdx.x;     // [n][c8][pix]
    int pix = idx & (HW_-1);
    int c8  = (idx >> 14) & 7;
    int n   = idx >> 17;
    const float* xp = x + ((size_t)(n*64 + c8*8))*HW_ + pix;
    short8 v;
    #pragma unroll
    for (int j = 0; j < 8; j++) v[j] = f2bf(xp[j*HW_]);
    xb8[idx] = v;
}

// ---------------- conv27 as implicit-GEMM bf16 MFMA (512 thr, B from global) ----
__global__ __launch_bounds__(512, 4) void conv27_mfma(
    const short8* __restrict__ xb8, const short8* __restrict__ btg,
    float* __restrict__ off_buf, float* __restrict__ filt_out)
{
    __shared__ short8 patch[8*325];   // [c8][py*18+px], plane stride 325
    const int tid = threadIdx.x;
    const int bx = blockIdx.x, by = blockIdx.y, n = blockIdx.z;

    for (int i = tid; i < 2592; i += 512) {
        int c8 = i / 324, r = i - c8*324;
        int py = r / 18, px = r - py*18;
        int gy = by*16 - 1 + py, gx = bx*16 - 1 + px;
        short8 v = {0,0,0,0,0,0,0,0};
        if ((unsigned)gy < 128u && (unsigned)gx < 128u)
            v = xb8[(size_t)(n*8 + c8)*HW_ + gy*W_ + gx];
        patch[c8*325 + py*18 + px] = v;
    }
    __syncthreads();

    const int lane = tid & 63, wid = tid >> 6;   // wid 0..7
    const int q = lane >> 4, col = lane & 15;
    float4_ acc[2][2];
    #pragma unroll
    for (int i = 0; i < 2; i++) {
        acc[i][0] = (float4_){0.f,0.f,0.f,0.f};
        acc[i][1] = (float4_){0.f,0.f,0.f,0.f};
    }

    #pragma unroll 2
    for (int k0 = 0; k0 < 18; k0++) {
        int t = k0 >> 1;
        int dy = t/3, dx = t - dy*3;
        int c8 = (k0 & 1)*4 + q;
        short8 b0 = btg[col*73 + k0*4 + q];
        short8 b1 = btg[(16 + col)*73 + k0*4 + q];
        #pragma unroll
        for (int i = 0; i < 2; i++) {
            int mt = wid*2 + i;
            short8 a = patch[c8*325 + (mt + dy)*18 + (col + dx)];
            acc[i][0] = __builtin_amdgcn_mfma_f32_16x16x32_bf16(a, b0, acc[i][0], 0,0,0);
            acc[i][1] = __builtin_amdgcn_mfma_f32_16x16x32_bf16(a, b1, acc[i][1], 0,0,0);
        }
    }

    // epilogue: float4 stores (reg -> 4 consecutive tx)
    #pragma unroll
    for (int i = 0; i < 2; i++) {
        int gy = by*16 + wid*2 + i;
        int pix0 = gy*W_ + bx*16 + q*4;
        #pragma unroll
        for (int nt = 0; nt < 2; nt++) {
            int oc = nt*16 + col;
            if (oc >= 27) continue;
            float4_ v = acc[i][nt];
            if (oc < 18)
                *(float4_*)&off_buf[((size_t)n*18 + oc)*HW_ + pix0] = v;
            else
                *(float4_*)&filt_out[((size_t)n*9 + (oc-18))*HW_ + pix0] = v;
        }
    }
}

// ---------------- deformable conv as MFMA GEMM, LDS-staged samples (512 thr) ----
__global__ __launch_bounds__(512, 4) void deform_mfma(
    const float* __restrict__ off_buf, const short8* __restrict__ xb8,
    const short8* __restrict__ wdefB, short* __restrict__ xr8s)
{
    __shared__ short8 patch[8*484];   // [c8][py*22+px], 61,952 B
    const int tid = threadIdx.x;
    const int bx = blockIdx.x, by = blockIdx.y, n = blockIdx.z;
    const int lane = tid & 63, wid = tid >> 6;   // 0..7
    const int q = lane >> 4, col = lane & 15;
    const int r0 = by*16 - 3, c0 = bx*16 - 3;
    const float*  ob    = off_buf + (size_t)n*18*HW_;
    const short8* xbase = xb8 + (size_t)n*8*HW_;
    const short*  xbs   = (const short*)xbase;

    for (int i = tid; i < 3872; i += 512) {
        int c8 = i / 484, r = i - c8*484;
        int py = r / 22, px = r - py*22;
        int gy = r0 + py, gx = c0 + px;
        short8 v = {0,0,0,0,0,0,0,0};
        if ((unsigned)gy < 128u && (unsigned)gx < 128u)
            v = xbase[(size_t)c8*HW_ + gy*W_ + gx];
        patch[c8*484 + r] = v;
    }
    __syncthreads();

    const int gxc = bx*16 + col;
    int pixi[2];
    #pragma unroll
    for (int i = 0; i < 2; i++) pixi[i] = (by*16 + wid*2 + i)*W_ + gxc;

    float4_ acc[2][4];
    #pragma unroll
    for (int i = 0; i < 2; i++)
        #pragma unroll
        for (int nt = 0; nt < 4; nt++) acc[i][nt] = (float4_){0.f,0.f,0.f,0.f};

    float oy[2], ox[2];
    #pragma unroll
    for (int i = 0; i < 2; i++) { oy[i] = ob[pixi[i]]; ox[i] = ob[HW_ + pixi[i]]; }

    #pragma unroll 1
    for (int t = 0; t < 9; t++) {
        const int dy = t/3 - 1, dx = (t - (t/3)*3) - 1;
        float oyn[2], oxn[2];
        if (t < 8) {
            #pragma unroll
            for (int i = 0; i < 2; i++) {
                oyn[i] = ob[(2*t+2)*HW_ + pixi[i]];
                oxn[i] = ob[(2*t+3)*HW_ + pixi[i]];
            }
        }
        short8 afrag[2][2];
        #pragma unroll
        for (int i = 0; i < 2; i++) {
            const int gy = by*16 + wid*2 + i;
            float py = (float)(gy + dy) + oy[i];
            float px = (float)(gxc + dx) + ox[i];
            float y0f = floorf(py), x0f = floorf(px);
            float wy1 = py - y0f, wx1 = px - x0f;
            float wy0 = 1.f - wy1, wx0 = 1.f - wx1;
            int y0 = (int)y0f, x0 = (int)x0f;
            int y1 = y0 + 1,   x1 = x0 + 1;
            float vy0 = ((unsigned)y0 < (unsigned)H_) ? 1.f : 0.f;
            float vy1 = ((unsigned)y1 < (unsigned)H_) ? 1.f : 0.f;
            float vx0 = ((unsigned)x0 < (unsigned)W_) ? 1.f : 0.f;
            float vx1 = ((unsigned)x1 < (unsigned)W_) ? 1.f : 0.f;
            float w00 = wy0*wx0*vy0*vx0, w01 = wy0*wx1*vy0*vx1;
            float w10 = wy1*wx0*vy1*vx0, w11 = wy1*wx1*vy1*vx1;
            int cy0 = min(max(y0, 0), H_-1), cy1 = min(max(y1, 0), H_-1);
            int cx0 = min(max(x0, 0), W_-1), cx1 = min(max(x1, 0), W_-1);
            int ly0 = cy0 - r0, ly1 = cy1 - r0;
            int lx0 = cx0 - c0, lx1 = cx1 - c0;
            bool inp = ((unsigned)ly0 < 22u) & ((unsigned)ly1 < 22u)
                     & ((unsigned)lx0 < 22u) & ((unsigned)lx1 < 22u);
            #pragma unroll
            for (int ks = 0; ks < 2; ks++) {
                const int c8 = ks*4 + q;
                short8 p00, p01, p10, p11;
                if (inp) {
                    const short8* pl = &patch[c8*484];
                    p00 = pl[ly0*22 + lx0]; p01 = pl[ly0*22 + lx1];
                    p10 = pl[ly1*22 + lx0]; p11 = pl[ly1*22 + lx1];
                } else {
                    const short8* xg = xbase + (size_t)c8*HW_;
                    p00 = xg[cy0*W_ + cx0]; p01 = xg[cy0*W_ + cx1];
                    p10 = xg[cy1*W_ + cx0]; p11 = xg[cy1*W_ + cx1];
                }
                short8 a;
                #pragma unroll
                for (int j = 0; j < 8; j++) {
                    float s = bf2f(p00[j])*w00 + bf2f(p01[j])*w01
                            + bf2f(p10[j])*w10 + bf2f(p11[j])*w11;
                    a[j] = f2bf(s);
                }
                afrag[i][ks] = a;
            }
        }
        #pragma unroll
        for (int ks = 0; ks < 2; ks++) {
            #pragma unroll
            for (int nt = 0; nt < 4; nt++) {
                short8 b = wdefB[(size_t)(nt*16 + col)*72 + t*8 + ks*4 + q];
                #pragma unroll
                for (int i = 0; i < 2; i++)
                    acc[i][nt] = __builtin_amdgcn_mfma_f32_16x16x32_bf16(
                        afrag[i][ks], b, acc[i][nt], 0,0,0);
            }
        }
        #pragma unroll
        for (int i = 0; i < 2; i++) { oy[i] = oyn[i]; ox[i] = oxn[i]; }
    }

    // epilogue: +bf16 residual, store NC8HW8 bf16
    short* xout = xr8s + (size_t)n*8*HW_*8;
    #pragma unroll
    for (int i = 0; i < 2; i++) {
        const int gy = by*16 + wid*2 + i;
        #pragma unroll
        for (int nt = 0; nt < 4; nt++) {
            const int o = nt*16 + col;
            #pragma unroll
            for (int reg = 0; reg < 4; reg++) {
                const int gx = bx*16 + q*4 + reg;
                const int pix = gy*W_ + gx;
                size_t si = ((size_t)(o >> 3)*HW_ + pix)*8 + (o & 7);
                float r = bf2f(xbs[si]);
                xout[si] = f2bf(acc[i][nt][reg] + r);
            }
        }
    }
}

// ---------------- conv9 + BN + ReLU as implicit-GEMM bf16 MFMA (512 thr) ------
__global__ __launch_bounds__(512, 4) void conv9_mfma(
    const short8* __restrict__ xr8, const short8* __restrict__ btg,
    const float* __restrict__ gamma, const float* __restrict__ beta,
    const float* __restrict__ mean, const float* __restrict__ var,
    float* __restrict__ out)
{
    __shared__ short8 patch[8*325];
    const int tid = threadIdx.x;
    const int bx = blockIdx.x, by = blockIdx.y, n = blockIdx.z;

    for (int i = tid; i < 2592; i += 512) {
        int c8 = i / 324, r = i - c8*324;
        int py = r / 18, px = r - py*18;
        int gy = by*16 - 1 + py, gx = bx*16 - 1 + px;
        short8 v = {0,0,0,0,0,0,0,0};
        if ((unsigned)gy < 128u && (unsigned)gx < 128u)
            v = xr8[(size_t)(n*8 + c8)*HW_ + gy*W_ + gx];
        patch[c8*325 + py*18 + px] = v;
    }
    __syncthreads();

    const int lane = tid & 63, wid = tid >> 6;
    const int q = lane >> 4, col = lane & 15;
    float4_ acc[2];
    #pragma unroll
    for (int i = 0; i < 2; i++) acc[i] = (float4_){0.f,0.f,0.f,0.f};

    #pragma unroll 2
    for (int k0 = 0; k0 < 18; k0++) {
        int t = k0 >> 1;
        int dy = t/3, dx = t - dy*3;
        int c8 = (k0 & 1)*4 + q;
        short8 b0 = btg[col*73 + k0*4 + q];
        #pragma unroll
        for (int i = 0; i < 2; i++) {
            int mt = wid*2 + i;
            short8 a = patch[c8*325 + (mt + dy)*18 + (col + dx)];
            acc[i] = __builtin_amdgcn_mfma_f32_16x16x32_bf16(a, b0, acc[i], 0,0,0);
        }
    }

    float sc = 0.f, sh = 0.f;
    if (col < 9) {
        sc = gamma[col] * rsqrtf(var[col] + BN_EPS);
        sh = beta[col] - mean[col] * sc;
    }
    #pragma unroll
    for (int i = 0; i < 2; i++) {
        int gy = by*16 + wid*2 + i;
        if (col < 9) {
            int pix0 = gy*W_ + bx*16 + q*4;
            float4_ v;
            #pragma unroll
            for (int reg = 0; reg < 4; reg++)
                v[reg] = fmaxf(fmaf(acc[i][reg], sc, sh), 0.f);
            *(float4_*)&out[((size_t)n*9 + col)*HW_ + pix0] = v;
        }
    }
}

extern "C" void kernel_launch(void* const* d_in, const int* in_sizes, int n_in,
                              void* d_out, int out_size, void* d_ws, size_t ws_size,
                              hipStream_t stream)
{
    const float* x     = (const float*)d_in[0];
    const float* w_off = (const float*)d_in[1];
    const float* w_def = (const float*)d_in[2];
    const float* w1    = (const float*)d_in[3];
    const float* gamma = (const float*)d_in[4];
    const float* beta  = (const float*)d_in[5];
    const float* mean  = (const float*)d_in[6];
    const float* var   = (const float*)d_in[7];
    float* out = (float*)d_out;

    char* ws = (char*)d_ws;
    float*  off_buf = (float*)(ws + OFFB_OFS);
    short8* xb8     = (short8*)(ws + XB8_OFS);
    short8* xr8     = (short8*)(ws + XR8_OFS);
    short*  wdefB   = (short*)(ws + WDEFB_OFS);
    short*  bt27    = (short*)(ws + BT27_OFS);
    short*  bt9     = (short*)(ws + BT9_OFS);

    float* h_out    = out;
    float* filt_out = out + (size_t)N_ * 9 * HW_;

    prep_w<<<dim3(254), dim3(256), 0, stream>>>(w_off, w_def, w1, wdefB, bt27, bt9);
    convert_x<<<dim3(4096), dim3(256), 0, stream>>>(x, xb8);

    dim3 cgrid(8, 8, 8);
    conv27_mfma<<<cgrid, dim3(512), 0, stream>>>(xb8, (const short8*)bt27, off_buf, filt_out);
    deform_mfma<<<cgrid, dim3(512), 0, stream>>>(off_buf, xb8, (const short8*)wdefB, (short*)xr8);
    conv9_mfma<<<cgrid, dim3(512), 0, stream>>>(xr8, (const short8*)bt9, gamma, beta, mean, var, h_out);
}

// Round 6
// 163.038 us; speedup vs baseline: 1.1386x; 1.1386x over previous
//
#include <hip/hip_runtime.h>
#include <cmath>

#define H_ 128
#define W_ 128
#define HW_ 16384
#define C_ 64
#define N_ 8
#define BN_EPS 1e-5f

typedef __attribute__((ext_vector_type(8))) short short8;
typedef __attribute__((ext_vector_type(4))) float float4_;

__device__ inline short f2bf(float f) {
    unsigned u = __builtin_bit_cast(unsigned, f);
    u += 0x7fffu + ((u >> 16) & 1u);     // RNE
    return (short)(u >> 16);
}
__device__ inline float bf2f(short s) {
    unsigned u = ((unsigned)(unsigned short)s) << 16;
    return __builtin_bit_cast(float, u);
}

// ---- workspace layout (bytes) ----
// xr8   bf16 [8][8][16384][8]  @ 0          size 16,777,216
// wdefB bf16 [64][576]         @ 16777216   size     73,728
// bt27  bf16 [32][584]         @ 16850944   size     37,376
// bt9   bf16 [16][584]         @ 16888320   size     18,688
#define XR8_OFS    0
#define WDEFB_OFS  16777216
#define BT27_OFS   16850944
#define BT9_OFS    16888320

// patch plane stride (short8 units): 402 so c8-plane offset = 1608 dwords,
// 1608 % 32 = 8 -> the 4 q-groups land on different bank quadrants.
#define PS_ 402
// offs row stride (floats): 260 (not 256) so oc rows don't alias bank 0.
#define OS_ 260

// ---------------- weight prep ----------------
__global__ __launch_bounds__(256) void prep_w(
    const float* __restrict__ w_off, const float* __restrict__ w_def,
    const float* __restrict__ w1, short* __restrict__ wdefB,
    short* __restrict__ bt27, short* __restrict__ bt9)
{
    int i = blockIdx.x * 256 + threadIdx.x;
    if (i < 36864) {
        int o = i / 576, r = i - o*576, t = r >> 6, c = r & 63;
        wdefB[i] = f2bf(w_def[o*576 + c*9 + t]);
    } else if (i < 36864 + 18688) {
        int j = i - 36864;
        int oc = j / 584, K = j - oc*584;
        float v = 0.f;
        if (oc < 27 && K < 576) { int t = K >> 6, c = K & 63; v = w_off[oc*576 + c*9 + t]; }
        bt27[j] = f2bf(v);
    } else if (i < 36864 + 18688 + 9344) {
        int j = i - 36864 - 18688;
        int oc = j / 584, K = j - oc*584;
        float v = 0.f;
        if (oc < 9 && K < 576) { int t = K >> 6, c = K & 63; v = w1[oc*576 + c*9 + t]; }
        bt9[j] = f2bf(v);
    }
}

// ======= fused: convert + conv27(offsets,filt) + deformable conv + residual ====
// block = 16x16 px tile, 256 thr (4 waves). Stage 20x20x64 bf16 patch (halo 2),
// conv27 via MFMA -> offsets to LDS / filt to global, then deform via MFMA with
// LDS corner reads (global fp32 fallback when sample leaves the halo window).
__global__ __launch_bounds__(256, 2) void fused_off_deform(
    const float* __restrict__ x, const short8* __restrict__ btg27,
    const short8* __restrict__ wdefB, float* __restrict__ filt_out,
    short* __restrict__ xr8s)
{
    __shared__ short8 patch[8*PS_];     // [c8][py*20+px], 51,456 B
    __shared__ float  offs[18*OS_];     // [och][row*16+col], 18,720 B
    const int tid = threadIdx.x;
    const int bx = blockIdx.x, by = blockIdx.y, n = blockIdx.z;
    const int lane = tid & 63, wid = tid >> 6;
    const int q = lane >> 4, col = lane & 15;
    const int r0 = by*16 - 2, c0 = bx*16 - 2;
    const float* xb = x + (size_t)n * C_ * HW_;

    // ---- stage 20x20 halo patch, fp32 -> bf16, NC8HW8 in LDS ----
    for (int i = tid; i < 3200; i += 256) {
        int c8 = i / 400, r = i - c8*400;
        int py = r / 20, px = r - py*20;
        int gy = r0 + py, gx = c0 + px;
        short8 v = {0,0,0,0,0,0,0,0};
        if ((unsigned)gy < 128u && (unsigned)gx < 128u) {
            const float* xp = xb + (size_t)(c8*8)*HW_ + gy*W_ + gx;
            #pragma unroll
            for (int j = 0; j < 8; j++) v[j] = f2bf(xp[j*HW_]);
        }
        patch[c8*PS_ + py*20 + px] = v;
    }
    __syncthreads();

    // ---- conv27 phase: M=256 px, N=32(27), K=576 ----
    {
        float4_ a27[4][2];
        #pragma unroll
        for (int i = 0; i < 4; i++) {
            a27[i][0] = (float4_){0.f,0.f,0.f,0.f};
            a27[i][1] = (float4_){0.f,0.f,0.f,0.f};
        }
        #pragma unroll 2
        for (int k0 = 0; k0 < 18; k0++) {
            int t = k0 >> 1;
            int dy = t/3, dx = t - dy*3;
            int c8 = (k0 & 1)*4 + q;
            short8 b0 = btg27[col*73 + k0*4 + q];
            short8 b1 = btg27[(16 + col)*73 + k0*4 + q];
            #pragma unroll
            for (int i = 0; i < 4; i++) {
                int mt = wid*4 + i;
                short8 a = patch[c8*PS_ + (mt + dy + 1)*20 + (col + dx + 1)];
                a27[i][0] = __builtin_amdgcn_mfma_f32_16x16x32_bf16(a, b0, a27[i][0], 0,0,0);
                a27[i][1] = __builtin_amdgcn_mfma_f32_16x16x32_bf16(a, b1, a27[i][1], 0,0,0);
            }
        }
        // D: row = q*4+reg = pixel col, tile row = mt; oc = nt*16 + col
        #pragma unroll
        for (int i = 0; i < 4; i++) {
            int mt = wid*4 + i;
            #pragma unroll
            for (int nt = 0; nt < 2; nt++) {
                int oc = nt*16 + col;
                if (oc < 18) {
                    *(float4_*)&offs[oc*OS_ + mt*16 + q*4] = a27[i][nt];
                } else if (oc < 27) {
                    int pix0 = (by*16 + mt)*W_ + bx*16 + q*4;
                    *(float4_*)&filt_out[((size_t)n*9 + (oc-18))*HW_ + pix0] = a27[i][nt];
                }
            }
        }
    }
    __syncthreads();

    // ---- deform phase: M=256 px, N=64, K=576 ----
    float4_ acc[4][4];
    #pragma unroll
    for (int i = 0; i < 4; i++)
        #pragma unroll
        for (int nt = 0; nt < 4; nt++) acc[i][nt] = (float4_){0.f,0.f,0.f,0.f};

    #pragma unroll 1
    for (int t = 0; t < 9; t++) {
        const int dy = t/3 - 1, dx = (t - (t/3)*3) - 1;
        short8 afrag[4][2];
        #pragma unroll
        for (int i = 0; i < 4; i++) {
            const int row = wid*4 + i;
            const int gy = by*16 + row, gxc = bx*16 + col;
            float oy = offs[(2*t)*OS_ + row*16 + col];
            float ox = offs[(2*t+1)*OS_ + row*16 + col];
            float py = (float)(gy + dy) + oy;
            float px = (float)(gxc + dx) + ox;
            float y0f = floorf(py), x0f = floorf(px);
            float wy1 = py - y0f, wx1 = px - x0f;
            float wy0 = 1.f - wy1, wx0 = 1.f - wx1;
            int y0 = (int)y0f, x0 = (int)x0f;
            int y1 = y0 + 1,   x1 = x0 + 1;
            float vy0 = ((unsigned)y0 < (unsigned)H_) ? 1.f : 0.f;
            float vy1 = ((unsigned)y1 < (unsigned)H_) ? 1.f : 0.f;
            float vx0 = ((unsigned)x0 < (unsigned)W_) ? 1.f : 0.f;
            float vx1 = ((unsigned)x1 < (unsigned)W_) ? 1.f : 0.f;
            float w00 = wy0*wx0*vy0*vx0, w01 = wy0*wx1*vy0*vx1;
            float w10 = wy1*wx0*vy1*vx0, w11 = wy1*wx1*vy1*vx1;
            int cy0 = min(max(y0, 0), H_-1), cy1 = min(max(y1, 0), H_-1);
            int cx0 = min(max(x0, 0), W_-1), cx1 = min(max(x1, 0), W_-1);
            int ly0 = cy0 - r0, ly1 = cy1 - r0;
            int lx0 = cx0 - c0, lx1 = cx1 - c0;
            bool inp = ((unsigned)ly0 < 20u) & ((unsigned)ly1 < 20u)
                     & ((unsigned)lx0 < 20u) & ((unsigned)lx1 < 20u);
            #pragma unroll
            for (int ks = 0; ks < 2; ks++) {
                const int c8 = ks*4 + q;
                short8 a;
                if (inp) {
                    const short8* pl = &patch[c8*PS_];
                    short8 p00 = pl[ly0*20 + lx0], p01 = pl[ly0*20 + lx1];
                    short8 p10 = pl[ly1*20 + lx0], p11 = pl[ly1*20 + lx1];
                    #pragma unroll
                    for (int j = 0; j < 8; j++) {
                        float s = bf2f(p00[j])*w00 + bf2f(p01[j])*w01
                                + bf2f(p10[j])*w10 + bf2f(p11[j])*w11;
                        a[j] = f2bf(s);
                    }
                } else {
                    // rare (|off| >= ~1): exact global fp32 fallback
                    const float* xg = xb + (size_t)(c8*8)*HW_;
                    #pragma unroll
                    for (int j = 0; j < 8; j++) {
                        const float* xj = xg + (size_t)j*HW_;
                        float s = xj[cy0*W_+cx0]*w00 + xj[cy0*W_+cx1]*w01
                                + xj[cy1*W_+cx0]*w10 + xj[cy1*W_+cx1]*w11;
                        a[j] = f2bf(s);
                    }
                }
                afrag[i][ks] = a;
            }
        }
        #pragma unroll
        for (int ks = 0; ks < 2; ks++) {
            #pragma unroll
            for (int nt = 0; nt < 4; nt++) {
                short8 b = wdefB[(size_t)(nt*16 + col)*72 + t*8 + ks*4 + q];
                #pragma unroll
                for (int i = 0; i < 4; i++)
                    acc[i][nt] = __builtin_amdgcn_mfma_f32_16x16x32_bf16(
                        afrag[i][ks], b, acc[i][nt], 0,0,0);
            }
        }
    }

    // ---- epilogue: +bf16 residual (from patch), store xr8 NC8HW8 bf16 ----
    const short* ps = (const short*)patch;
    short* xout = xr8s + (size_t)n*8*HW_*8;
    #pragma unroll
    for (int i = 0; i < 4; i++) {
        const int row = wid*4 + i;
        const int gy = by*16 + row;
        #pragma unroll
        for (int nt = 0; nt < 4; nt++) {
            const int o = nt*16 + col;
            #pragma unroll
            for (int reg = 0; reg < 4; reg++) {
                const int m = q*4 + reg;
                const int pix = gy*W_ + bx*16 + m;
                float r = bf2f(ps[(((o>>3)*PS_ + (row+2)*20 + (m+2)) << 3) + (o & 7)]);
                xout[((size_t)(o>>3)*HW_ + pix)*8 + (o & 7)] = f2bf(acc[i][nt][reg] + r);
            }
        }
    }
}

// ---------------- conv9 + BN + ReLU as implicit-GEMM bf16 MFMA ----------------
__global__ __launch_bounds__(256) void conv9_mfma(
    const short8* __restrict__ xr8, const short* __restrict__ bt_g,
    const float* __restrict__ gamma, const float* __restrict__ beta,
    const float* __restrict__ mean, const float* __restrict__ var,
    float* __restrict__ out)
{
    __shared__ short8 patch[8*325];
    __shared__ short8 btl[16*73];
    const int tid = threadIdx.x;
    const int bx = blockIdx.x, by = blockIdx.y, n = blockIdx.z;

    for (int i = tid; i < 1168; i += 256) btl[i] = ((const short8*)bt_g)[i];
    for (int i = tid; i < 2592; i += 256) {
        int c8 = i / 324, r = i - c8*324;
        int py = r / 18, px = r - py*18;
        int gy = by*16 - 1 + py, gx = bx*16 - 1 + px;
        short8 v = {0,0,0,0,0,0,0,0};
        if ((unsigned)gy < 128u && (unsigned)gx < 128u)
            v = xr8[(size_t)(n*8 + c8)*HW_ + gy*W_ + gx];
        patch[c8*325 + py*18 + px] = v;
    }
    __syncthreads();

    const int lane = tid & 63, wid = tid >> 6;
    const int q = lane >> 4, col = lane & 15;
    float4_ acc[4];
    #pragma unroll
    for (int i = 0; i < 4; i++) acc[i] = (float4_){0.f,0.f,0.f,0.f};

    #pragma unroll 2
    for (int k0 = 0; k0 < 18; k0++) {
        int t = k0 >> 1;
        int dy = t/3, dx = t - dy*3;
        int c8 = (k0 & 1)*4 + q;
        short8 b0 = btl[col*73 + k0*4 + q];
        #pragma unroll
        for (int i = 0; i < 4; i++) {
            int mt = wid*4 + i;
            short8 a = patch[c8*325 + (mt + dy)*18 + (col + dx)];
            acc[i] = __builtin_amdgcn_mfma_f32_16x16x32_bf16(a, b0, acc[i], 0,0,0);
        }
    }

    float sc = 0.f, sh = 0.f;
    if (col < 9) {
        sc = gamma[col] * rsqrtf(var[col] + BN_EPS);
        sh = beta[col] - mean[col] * sc;
    }
    #pragma unroll
    for (int i = 0; i < 4; i++) {
        int mt = wid*4 + i;
        if (col < 9) {
            int pix0 = (by*16 + mt)*W_ + bx*16 + q*4;
            float4_ v;
            #pragma unroll
            for (int reg = 0; reg < 4; reg++)
                v[reg] = fmaxf(fmaf(acc[i][reg], sc, sh), 0.f);
            *(float4_*)&out[((size_t)n*9 + col)*HW_ + pix0] = v;
        }
    }
}

extern "C" void kernel_launch(void* const* d_in, const int* in_sizes, int n_in,
                              void* d_out, int out_size, void* d_ws, size_t ws_size,
                              hipStream_t stream)
{
    const float* x     = (const float*)d_in[0];
    const float* w_off = (const float*)d_in[1];
    const float* w_def = (const float*)d_in[2];
    const float* w1    = (const float*)d_in[3];
    const float* gamma = (const float*)d_in[4];
    const float* beta  = (const float*)d_in[5];
    const float* mean  = (const float*)d_in[6];
    const float* var   = (const float*)d_in[7];
    float* out = (float*)d_out;

    char* ws = (char*)d_ws;
    short8* xr8     = (short8*)(ws + XR8_OFS);
    short*  wdefB   = (short*)(ws + WDEFB_OFS);
    short*  bt27    = (short*)(ws + BT27_OFS);
    short*  bt9     = (short*)(ws + BT9_OFS);

    float* h_out    = out;
    float* filt_out = out + (size_t)N_ * 9 * HW_;

    prep_w<<<dim3(254), dim3(256), 0, stream>>>(w_off, w_def, w1, wdefB, bt27, bt9);

    dim3 cgrid(8, 8, 8);
    fused_off_deform<<<cgrid, dim3(256), 0, stream>>>(
        x, (const short8*)bt27, (const short8*)wdefB, filt_out, (short*)xr8);
    conv9_mfma<<<cgrid, dim3(256), 0, stream>>>(xr8, bt9, gamma, beta, mean, var, h_out);
}

// Round 8
// 157.181 us; speedup vs baseline: 1.1811x; 1.0373x over previous
//
#include <hip/hip_runtime.h>
#include <hip/hip_bf16.h>
#include <cmath>

#define H_ 128
#define W_ 128
#define HW_ 16384
#define C_ 64
#define N_ 8
#define BN_EPS 1e-5f

typedef __attribute__((ext_vector_type(8))) short short8;
typedef __attribute__((ext_vector_type(4))) float float4_;
typedef __attribute__((ext_vector_type(4))) unsigned uint4_;

__device__ inline short f2bf(float f) {
    unsigned u = __builtin_bit_cast(unsigned, f);
    u += 0x7fffu + ((u >> 16) & 1u);     // RNE
    return (short)(u >> 16);
}
__device__ inline float bf2f(short s) {
    unsigned u = ((unsigned)(unsigned short)s) << 16;
    return __builtin_bit_cast(float, u);
}
// packed RNE fp32x2 -> bf16x2 (v_cvt_pk_bf16_f32 on gfx950)
__device__ inline unsigned pkbf2(float a, float b) {
    __hip_bfloat162 h = __float22bfloat162_rn(make_float2(a, b));
    unsigned u;
    __builtin_memcpy(&u, &h, 4);
    return u;
}
__device__ inline float bperm_f(int addr, float v) {
    return __builtin_bit_cast(float,
        __builtin_amdgcn_ds_bpermute(addr, __builtin_bit_cast(int, v)));
}

// ---- workspace layout (bytes) ----
#define XR8_OFS    0
#define WDEFB_OFS  16777216
#define BT27_OFS   16850944
#define BT9_OFS    16888320

#define PS_ 402   // patch plane stride (short8): c8-plane offset 1608 dw, %32=8

// ---------------- weight prep ----------------
__global__ __launch_bounds__(256) void prep_w(
    const float* __restrict__ w_off, const float* __restrict__ w_def,
    const float* __restrict__ w1, short* __restrict__ wdefB,
    short* __restrict__ bt27, short* __restrict__ bt9)
{
    int i = blockIdx.x * 256 + threadIdx.x;
    if (i < 36864) {
        int o = i / 576, r = i - o*576, t = r >> 6, c = r & 63;
        wdefB[i] = f2bf(w_def[o*576 + c*9 + t]);
    } else if (i < 36864 + 18688) {
        int j = i - 36864;
        int oc = j / 584, K = j - oc*584;
        float v = 0.f;
        if (oc < 27 && K < 576) { int t = K >> 6, c = K & 63; v = w_off[oc*576 + c*9 + t]; }
        bt27[j] = f2bf(v);
    } else if (i < 36864 + 18688 + 9344) {
        int j = i - 36864 - 18688;
        int oc = j / 584, K = j - oc*584;
        float v = 0.f;
        if (oc < 9 && K < 576) { int t = K >> 6, c = K & 63; v = w1[oc*576 + c*9 + t]; }
        bt9[j] = f2bf(v);
    }
}

// ======= fused: convert + conv27(offsets,filt) + deformable conv + residual ====
// 16x16 px tile, 256 thr (4 waves). One barrier total. conv27 computed with
// swapped MFMA operands so D = [oc][pixel_col]; offsets reach the deform phase
// via ds_bpermute (no offs LDS, no second barrier).
__global__ __launch_bounds__(256, 2) void fused_off_deform(
    const float* __restrict__ x, const short8* __restrict__ btg27,
    const short8* __restrict__ wdefB, float* __restrict__ filt_out,
    short* __restrict__ xr8s)
{
    __shared__ short8 patch[8*PS_];     // [c8][py*20+px], 51,456 B
    const int tid = threadIdx.x;
    const int bx = blockIdx.x, by = blockIdx.y, n = blockIdx.z;
    const int lane = tid & 63, wid = tid >> 6;
    const int q = lane >> 4, col = lane & 15;
    const int r0 = by*16 - 2, c0 = bx*16 - 2;
    const float* xb = x + (size_t)n * C_ * HW_;

    // ---- stage 20x20 halo patch, fp32 -> bf16 (packed cvt), NC8HW8 in LDS ----
    for (int i = tid; i < 3200; i += 256) {
        int c8 = i / 400, r = i - c8*400;
        int py = r / 20, px = r - py*20;
        int gy = r0 + py, gx = c0 + px;
        uint4_ u = (uint4_){0u,0u,0u,0u};
        if ((unsigned)gy < 128u && (unsigned)gx < 128u) {
            const float* xp = xb + (size_t)(c8*8)*HW_ + gy*W_ + gx;
            u[0] = pkbf2(xp[0],      xp[HW_]);
            u[1] = pkbf2(xp[2*HW_],  xp[3*HW_]);
            u[2] = pkbf2(xp[4*HW_],  xp[5*HW_]);
            u[3] = pkbf2(xp[6*HW_],  xp[7*HW_]);
        }
        patch[c8*PS_ + py*20 + px] = __builtin_bit_cast(short8, u);
    }
    __syncthreads();

    // ---- conv27 phase (swapped: A=weights, B=patch) -> D[oc][pixel_col] ----
    float4_ a27[2][4];      // [oc-tile][row i]
    #pragma unroll
    for (int m = 0; m < 2; m++)
        #pragma unroll
        for (int i = 0; i < 4; i++) a27[m][i] = (float4_){0.f,0.f,0.f,0.f};

    #pragma unroll 2
    for (int k0 = 0; k0 < 18; k0++) {
        int t = k0 >> 1;
        int dy = t/3, dx = t - dy*3;
        int c8 = (k0 & 1)*4 + q;
        short8 w0 = btg27[col*73 + k0*4 + q];
        short8 w1 = btg27[(16 + col)*73 + k0*4 + q];
        #pragma unroll
        for (int i = 0; i < 4; i++) {
            int mt = wid*4 + i;
            short8 p = patch[c8*PS_ + (mt + dy + 1)*20 + (col + dx + 1)];
            a27[0][i] = __builtin_amdgcn_mfma_f32_16x16x32_bf16(w0, p, a27[0][i], 0,0,0);
            a27[1][i] = __builtin_amdgcn_mfma_f32_16x16x32_bf16(w1, p, a27[1][i], 0,0,0);
        }
    }

    // filt (oc 18..26) store: oc = 16 + q*4 + reg, pixel (row=wid*4+i, col)
    #pragma unroll
    for (int i = 0; i < 4; i++) {
        int prow = by*16 + wid*4 + i;
        #pragma unroll
        for (int reg = 0; reg < 4; reg++) {
            int oc = 16 + q*4 + reg;
            if (oc >= 18 && oc < 27)
                filt_out[((size_t)n*9 + (oc-18))*HW_ + prow*W_ + bx*16 + col] = a27[1][i][reg];
        }
    }

    // ---- deform phase: M=16 pixel_cols x 4 rows/wave, N=64, K=576 ----
    float4_ acc[4][4];
    #pragma unroll
    for (int i = 0; i < 4; i++)
        #pragma unroll
        for (int nt = 0; nt < 4; nt++) acc[i][nt] = (float4_){0.f,0.f,0.f,0.f};

    const int col4 = col*4;
    const int gxc = bx*16 + col;

    // one tap of the deformable conv
    auto tap = [&](int t, int dy, int dx, const float* oy, const float* ox) {
        short8 afrag[4][2];
        #pragma unroll
        for (int i = 0; i < 4; i++) {
            const int gy = by*16 + wid*4 + i;
            float py = (float)(gy + dy) + oy[i];
            float px = (float)(gxc + dx) + ox[i];
            float y0f = floorf(py), x0f = floorf(px);
            float wy1 = py - y0f, wx1 = px - x0f;
            float wy0 = 1.f - wy1, wx0 = 1.f - wx1;
            int y0 = (int)y0f, x0 = (int)x0f;
            int y1 = y0 + 1,   x1 = x0 + 1;
            // fold validity into the 1-D weights
            float wy0v = ((unsigned)y0 < (unsigned)H_) ? wy0 : 0.f;
            float wy1v = ((unsigned)y1 < (unsigned)H_) ? wy1 : 0.f;
            float wx0v = ((unsigned)x0 < (unsigned)W_) ? wx0 : 0.f;
            float wx1v = ((unsigned)x1 < (unsigned)W_) ? wx1 : 0.f;
            float w00 = wy0v*wx0v, w01 = wy0v*wx1v;
            float w10 = wy1v*wx0v, w11 = wy1v*wx1v;
            int cy0 = min(max(y0, 0), H_-1), cy1 = min(max(y1, 0), H_-1);
            int cx0 = min(max(x0, 0), W_-1), cx1 = min(max(x1, 0), W_-1);
            int ly0 = cy0 - r0, ly1 = cy1 - r0;
            int lx0 = cx0 - c0, lx1 = cx1 - c0;
            bool inp = ((unsigned)ly0 < 20u) & ((unsigned)ly1 < 20u)
                     & ((unsigned)lx0 < 20u) & ((unsigned)lx1 < 20u);
            #pragma unroll
            for (int ks = 0; ks < 2; ks++) {
                const int c8 = ks*4 + q;
                uint4_ u;
                if (inp) {
                    const short8* pl = &patch[c8*PS_];
                    short8 p00 = pl[ly0*20 + lx0], p01 = pl[ly0*20 + lx1];
                    short8 p10 = pl[ly1*20 + lx0], p11 = pl[ly1*20 + lx1];
                    float s[8];
                    #pragma unroll
                    for (int j = 0; j < 8; j++)
                        s[j] = bf2f(p00[j])*w00 + bf2f(p01[j])*w01
                             + bf2f(p10[j])*w10 + bf2f(p11[j])*w11;
                    u[0] = pkbf2(s[0],s[1]); u[1] = pkbf2(s[2],s[3]);
                    u[2] = pkbf2(s[4],s[5]); u[3] = pkbf2(s[6],s[7]);
                } else {
                    // rare (|off| >= ~1): exact global fp32 fallback
                    const float* xg = xb + (size_t)(c8*8)*HW_;
                    float s[8];
                    #pragma unroll
                    for (int j = 0; j < 8; j++) {
                        const float* xj = xg + (size_t)j*HW_;
                        s[j] = xj[cy0*W_+cx0]*w00 + xj[cy0*W_+cx1]*w01
                             + xj[cy1*W_+cx0]*w10 + xj[cy1*W_+cx1]*w11;
                    }
                    u[0] = pkbf2(s[0],s[1]); u[1] = pkbf2(s[2],s[3]);
                    u[2] = pkbf2(s[4],s[5]); u[3] = pkbf2(s[6],s[7]);
                }
                afrag[i][ks] = __builtin_bit_cast(short8, u);
            }
        }
        #pragma unroll
        for (int ks = 0; ks < 2; ks++) {
            #pragma unroll
            for (int nt = 0; nt < 4; nt++) {
                short8 b = wdefB[(size_t)(nt*16 + col)*72 + t*8 + ks*4 + q];
                #pragma unroll
                for (int i = 0; i < 4; i++)
                    acc[i][nt] = __builtin_amdgcn_mfma_f32_16x16x32_bf16(
                        afrag[i][ks], b, acc[i][nt], 0,0,0);
            }
        }
    };

    // ---- tap t=8 first (offsets oc 16,17 live in a27[1] regs 0,1) ----
    {
        float oy[4], ox[4];
        #pragma unroll
        for (int i = 0; i < 4; i++) {
            oy[i] = bperm_f(col4, a27[1][i][0]);
            ox[i] = bperm_f(col4, a27[1][i][1]);
        }
        tap(8, 1, 1, oy, ox);      // a27[1] dead after this point
    }
    // ---- taps t=0..7 (offsets oc 2t,2t+1 in a27[0]; reg parity by t&1) ----
    #pragma unroll 1
    for (int t = 0; t < 8; t++) {
        const int addr = ((t >> 1) << 6) + col4;   // src lane = (2t>>2)*16 + col
        float oy[4], ox[4];
        #pragma unroll
        for (int i = 0; i < 4; i++) {
            float oyA = bperm_f(addr, a27[0][i][0]);
            float oyB = bperm_f(addr, a27[0][i][2]);
            float oxA = bperm_f(addr, a27[0][i][1]);
            float oxB = bperm_f(addr, a27[0][i][3]);
            oy[i] = (t & 1) ? oyB : oyA;
            ox[i] = (t & 1) ? oxB : oxA;
        }
        int dy = t/3 - 1, dx = (t - (t/3)*3) - 1;
        tap(t, dy, dx, oy, ox);
    }

    // ---- epilogue: +bf16 residual (from patch), store xr8 NC8HW8 bf16 ----
    const short* ps = (const short*)patch;
    short* xout = xr8s + (size_t)n*8*HW_*8;
    #pragma unroll
    for (int i = 0; i < 4; i++) {
        const int row = wid*4 + i;
        const int gy = by*16 + row;
        #pragma unroll
        for (int nt = 0; nt < 4; nt++) {
            const int o = nt*16 + col;
            #pragma unroll
            for (int reg = 0; reg < 4; reg++) {
                const int m = q*4 + reg;
                const int pix = gy*W_ + bx*16 + m;
                float r = bf2f(ps[(((o>>3)*PS_ + (row+2)*20 + (m+2)) << 3) + (o & 7)]);
                xout[((size_t)(o>>3)*HW_ + pix)*8 + (o & 7)] = f2bf(acc[i][nt][reg] + r);
            }
        }
    }
}

// ---------------- conv9 + BN + ReLU (B direct from global, L1-hot) -----------
__global__ __launch_bounds__(256) void conv9_mfma(
    const short8* __restrict__ xr8, const short8* __restrict__ btg,
    const float* __restrict__ gamma, const float* __restrict__ beta,
    const float* __restrict__ mean, const float* __restrict__ var,
    float* __restrict__ out)
{
    __shared__ short8 patch[8*325];
    const int tid = threadIdx.x;
    const int bx = blockIdx.x, by = blockIdx.y, n = blockIdx.z;

    for (int i = tid; i < 2592; i += 256) {
        int c8 = i / 324, r = i - c8*324;
        int py = r / 18, px = r - py*18;
        int gy = by*16 - 1 + py, gx = bx*16 - 1 + px;
        short8 v = {0,0,0,0,0,0,0,0};
        if ((unsigned)gy < 128u && (unsigned)gx < 128u)
            v = xr8[(size_t)(n*8 + c8)*HW_ + gy*W_ + gx];
        patch[c8*325 + py*18 + px] = v;
    }
    __syncthreads();

    const int lane = tid & 63, wid = tid >> 6;
    const int q = lane >> 4, col = lane & 15;
    float4_ acc[4];
    #pragma unroll
    for (int i = 0; i < 4; i++) acc[i] = (float4_){0.f,0.f,0.f,0.f};

    #pragma unroll 2
    for (int k0 = 0; k0 < 18; k0++) {
        int t = k0 >> 1;
        int dy = t/3, dx = t - dy*3;
        int c8 = (k0 & 1)*4 + q;
        short8 b0 = btg[col*73 + k0*4 + q];
        #pragma unroll
        for (int i = 0; i < 4; i++) {
            int mt = wid*4 + i;
            short8 a = patch[c8*325 + (mt + dy)*18 + (col + dx)];
            acc[i] = __builtin_amdgcn_mfma_f32_16x16x32_bf16(a, b0, acc[i], 0,0,0);
        }
    }

    float sc = 0.f, sh = 0.f;
    if (col < 9) {
        sc = gamma[col] * rsqrtf(var[col] + BN_EPS);
        sh = beta[col] - mean[col] * sc;
    }
    #pragma unroll
    for (int i = 0; i < 4; i++) {
        int mt = wid*4 + i;
        if (col < 9) {
            int pix0 = (by*16 + mt)*W_ + bx*16 + q*4;
            float4_ v;
            #pragma unroll
            for (int reg = 0; reg < 4; reg++)
                v[reg] = fmaxf(fmaf(acc[i][reg], sc, sh), 0.f);
            *(float4_*)&out[((size_t)n*9 + col)*HW_ + pix0] = v;
        }
    }
}

extern "C" void kernel_launch(void* const* d_in, const int* in_sizes, int n_in,
                              void* d_out, int out_size, void* d_ws, size_t ws_size,
                              hipStream_t stream)
{
    const float* x     = (const float*)d_in[0];
    const float* w_off = (const float*)d_in[1];
    const float* w_def = (const float*)d_in[2];
    const float* w1    = (const float*)d_in[3];
    const float* gamma = (const float*)d_in[4];
    const float* beta  = (const float*)d_in[5];
    const float* mean  = (const float*)d_in[6];
    const float* var   = (const float*)d_in[7];
    float* out = (float*)d_out;

    char* ws = (char*)d_ws;
    short8* xr8     = (short8*)(ws + XR8_OFS);
    short*  wdefB   = (short*)(ws + WDEFB_OFS);
    short*  bt27    = (short*)(ws + BT27_OFS);
    short*  bt9     = (short*)(ws + BT9_OFS);

    float* h_out    = out;
    float* filt_out = out + (size_t)N_ * 9 * HW_;

    prep_w<<<dim3(254), dim3(256), 0, stream>>>(w_off, w_def, w1, wdefB, bt27, bt9);

    dim3 cgrid(8, 8, 8);
    fused_off_deform<<<cgrid, dim3(256), 0, stream>>>(
        x, (const short8*)bt27, (const short8*)wdefB, filt_out, (short*)xr8);
    conv9_mfma<<<cgrid, dim3(256), 0, stream>>>(
        xr8, (const short8*)bt9, gamma, beta, mean, var, h_out);
}